// Round 9
// baseline (215.062 us; speedup 1.0000x reference)
//
#include <hip/hip_runtime.h>
#include <math.h>

typedef __attribute__((ext_vector_type(8))) short bvec8;   // 8 bf16 (4 VGPRs)
typedef __attribute__((ext_vector_type(4))) short bvec4;
typedef __attribute__((ext_vector_type(4))) float fvec4;
typedef unsigned short u16;

#define MROWS 16384
#define TLEN  4096
#define DD    512
#define SWB   384
#define NT128 32
#define EPS_RMS 1.1920929e-07f

#define M_QK     0
#define M_VT     1
#define M_SCORE  2
#define M_RET    3
#define M_ORES   4
#define M_RSCALE 5
#define M_GELU   6
#define M_F32RES 7

__device__ __forceinline__ u16 f2bf(float f) {
  unsigned int u = __float_as_uint(f);
  u = (u + 0x7fffu + ((u >> 16) & 1u)) >> 16;   // RNE
  return (u16)u;
}

__device__ __forceinline__ float wred_sum(float v) {
#pragma unroll
  for (int off = 32; off > 0; off >>= 1) v += __shfl_xor(v, off, 64);
  return v;
}
__device__ __forceinline__ float wred_max(float v) {
#pragma unroll
  for (int off = 32; off > 0; off >>= 1) v = fmaxf(v, __shfl_xor(v, off, 64));
  return v;
}

__device__ __forceinline__ int xcd_swz(int bid, int chunk) {
  return (bid & 7) * chunk + (bid >> 3);
}

#define GL16(g, l) __builtin_amdgcn_global_load_lds((const __attribute__((address_space(1))) unsigned int*)(g), (__attribute__((address_space(3))) unsigned int*)(l), 16, 0, 0)

// ========== hybrid 128x128xK core: stage ONE operand in LDS, direct-load the other ==========
// LDS: 2 buf x 8192 shorts (16 KB) = 32 KB. Staged rows 128 x 64k, 16B-slot XOR (row&7).
// Per tile: [8 direct frag loads][4 stage GL16 (j+1)] | ks0: 4 ds_read + 16 MFMA |
// ks1: 4 ds_read + 16 MFMA | vmcnt(0)+lgkmcnt(0)+barrier. Direct loads are OLDER than
// stages, so compiler-inserted waits for them (vmcnt(8)/vmcnt(4)) never drain stages.
template<bool STAGED_A, bool PACKED>
__device__ __forceinline__ void gcore_h(
    const u16* __restrict__ Sg, int lda,
    const u16* __restrict__ Dn, int ldb,          // natural direct (PACKED=0)
    const u16* __restrict__ Dp, int db16,         // packed direct (PACKED=1), nks=16 slices
    u16* lds, int NT, int tid, int woffS, int woffD,
    fvec4 (*acc)[4], int nks)
{
  const int lane = tid & 63;
  const int w = tid >> 6;
  const int r = lane & 15, kg = lane >> 4;
  const int ar = tid >> 3, as = (tid & 7) ^ (ar & 7);
  const u16* s0p = Sg + (size_t)ar * lda + as * 8;
  const u16* s1p = s0p + (size_t)32 * lda;
  const u16* s2p = s0p + (size_t)64 * lda;
  const u16* s3p = s0p + (size_t)96 * lda;
  u16* ldsw = lds + w * 512;                       // + lane*16B implicit in HW
  int cur = 0;

#define STG(kt,p) { GL16(s0p+(kt)*64, ldsw+(p)*8192);      GL16(s1p+(kt)*64, ldsw+(p)*8192+2048); \
                    GL16(s2p+(kt)*64, ldsw+(p)*8192+4096); GL16(s3p+(kt)*64, ldsw+(p)*8192+6144); }
  STG(0, 0);
  asm volatile("s_waitcnt vmcnt(0)" ::: "memory");
  __builtin_amdgcn_s_barrier();
  asm volatile("" ::: "memory");

  for (int j = 0; j < NT; ++j) {
    bvec8 d0[4], d1[4];
#pragma unroll
    for (int f = 0; f < 4; ++f) {
      if constexpr (PACKED) {
        size_t g = (size_t)(db16 + (woffD >> 4) + f) * nks;
        d0[f] = *(const bvec8*)&Dp[(g + (j*2+0)) * 512 + lane * 8];
        d1[f] = *(const bvec8*)&Dp[(g + (j*2+1)) * 512 + lane * 8];
      } else {
        const u16* p = Dn + (size_t)(woffD + f*16 + r) * ldb + j*64 + kg*8;
        d0[f] = *(const bvec8*)p;
        d1[f] = *(const bvec8*)(p + 32);
      }
    }
    __builtin_amdgcn_sched_barrier(0);
    if (j + 1 < NT) { STG(j + 1, cur ^ 1); }
    __builtin_amdgcn_sched_barrier(0);
    const u16* buf = lds + cur * 8192;
    bvec8 s0[4], s1[4];
#pragma unroll
    for (int f = 0; f < 4; ++f) {
      int rr = woffS + f*16 + r;
      s0[f] = *(const bvec8*)&buf[rr*64 + ((kg) ^ (rr & 7)) * 8];
    }
    __builtin_amdgcn_s_setprio(1);
#pragma unroll
    for (int a = 0; a < 4; ++a)
#pragma unroll
      for (int b = 0; b < 4; ++b)
        acc[a][b] = __builtin_amdgcn_mfma_f32_16x16x32_bf16(
            STAGED_A ? s0[a] : d0[a], STAGED_A ? d0[b] : s0[b], acc[a][b], 0, 0, 0);
    __builtin_amdgcn_s_setprio(0);
#pragma unroll
    for (int f = 0; f < 4; ++f) {
      int rr = woffS + f*16 + r;
      s1[f] = *(const bvec8*)&buf[rr*64 + ((4 + kg) ^ (rr & 7)) * 8];
    }
    __builtin_amdgcn_s_setprio(1);
#pragma unroll
    for (int a = 0; a < 4; ++a)
#pragma unroll
      for (int b = 0; b < 4; ++b)
        acc[a][b] = __builtin_amdgcn_mfma_f32_16x16x32_bf16(
            STAGED_A ? s1[a] : d1[a], STAGED_A ? d1[b] : s1[b], acc[a][b], 0, 0, 0);
    __builtin_amdgcn_s_setprio(0);
    if (j + 1 < NT) {
      asm volatile("s_waitcnt vmcnt(0) lgkmcnt(0)" ::: "memory");
      __builtin_amdgcn_s_barrier();
      asm volatile("" ::: "memory");
      cur ^= 1;
    }
  }
#undef STG
}

// ---- convert the 7 fp32 param arrays ([512][128]) to bf16 ----
__global__ __launch_bounds__(256) void conv7_kernel(
    const float* __restrict__ basis, const float* __restrict__ qc, const float* __restrict__ kc,
    const float* __restrict__ vc, const float* __restrict__ oc, const float* __restrict__ rc,
    const float* __restrict__ wc,
    u16* __restrict__ basisb, u16* __restrict__ qcb, u16* __restrict__ kcb,
    u16* __restrict__ vcb, u16* __restrict__ ocb, u16* __restrict__ rcb,
    u16* __restrict__ wcb)
{
  const float* src; u16* dst;
  switch (blockIdx.y) {
    case 0: src = basis; dst = basisb; break;
    case 1: src = qc; dst = qcb; break;
    case 2: src = kc; dst = kcb; break;
    case 3: src = vc; dst = vcb; break;
    case 4: src = oc; dst = ocb; break;
    case 5: src = rc; dst = rcb; break;
    default: src = wc; dst = wcb; break;
  }
  int idx = blockIdx.x * 256 + threadIdx.x;
  float4 v = ((const float4*)src)[idx];
  union { bvec4 s; u16 u[4]; } o;
  o.u[0] = f2bf(v.x); o.u[1] = f2bf(v.y); o.u[2] = f2bf(v.z); o.u[3] = f2bf(v.w);
  ((bvec4*)dst)[idx] = o.s;
}

// ---- fused 6x weight-gen GEMM (512x512, K=128): hybrid core, natural direct ----
__global__ __launch_bounds__(256, 3) void wgen_kernel(
    const u16* __restrict__ basisb, const u16* __restrict__ qcb,
    const u16* __restrict__ kcb, const u16* __restrict__ vcb,
    const u16* __restrict__ ocb, const u16* __restrict__ wcb,
    const u16* __restrict__ rcb,
    u16* __restrict__ qwT, u16* __restrict__ kwT,
    u16* __restrict__ vwT, u16* __restrict__ owB,
    u16* __restrict__ wrB, float* __restrict__ readLog)
{
  __shared__ __align__(16) u16 lds[16384];
  int tid = threadIdx.x, lane = tid & 63, wave = tid >> 6;
  int wm = (wave >> 1) * 64, wn = (wave & 1) * 64;
  int z = blockIdx.z;
  const u16 *Az, *Bz;
  switch (z) {
    case 0: Az = qcb;    Bz = basisb; break;
    case 1: Az = kcb;    Bz = basisb; break;
    case 2: Az = vcb;    Bz = basisb; break;
    case 3: Az = basisb; Bz = ocb;    break;
    case 4: Az = basisb; Bz = wcb;    break;
    default: Az = rcb;   Bz = basisb; break;
  }
  fvec4 acc[4][4] = {};
  gcore_h<true, false>(Az + (size_t)blockIdx.y * 128 * 128, 128,
                       Bz + (size_t)blockIdx.x * 128 * 128, 128,
                       nullptr, 0, lds, 2, tid, wm, wn, acc, 0);
  int l15 = lane & 15, lr4 = (lane >> 4) << 2;
  int om = blockIdx.y * 128, on = blockIdx.x * 128;
  u16* oz = (z == 0) ? qwT : (z == 1) ? kwT : (z == 2) ? vwT : (z == 3) ? owB : wrB;
#pragma unroll
  for (int mi = 0; mi < 4; ++mi)
#pragma unroll
    for (int ni = 0; ni < 4; ++ni)
#pragma unroll
      for (int j = 0; j < 4; ++j) {
        int rr = om + wm + mi * 16 + lr4 + j;
        int c = on + wn + ni * 16 + l15;
        float v = acc[mi][ni][j];
        if (z == 5) readLog[(size_t)rr * DD + c] = v;
        else        oz[(size_t)rr * DD + c] = f2bf(v);
      }
}

// ---- repack weights into MFMA fragment order [g16][kslice(16)][lane(64)][8] ----
// y: 0 qwT->qkF[0:32) 1 kwT->qkF[32:64) 2 vwT->vwF 3 owB->owF 4 rdB->rdF 5 wrB->wrF 6 mtB->mtF
__global__ __launch_bounds__(256) void repack7_kernel(
    const u16* __restrict__ qwT, const u16* __restrict__ kwT, const u16* __restrict__ vwT,
    const u16* __restrict__ owB, const u16* __restrict__ rdB, const u16* __restrict__ wrB,
    const u16* __restrict__ mtB,
    u16* __restrict__ qkF, u16* __restrict__ vwF, u16* __restrict__ owF,
    u16* __restrict__ rdF, u16* __restrict__ wrF, u16* __restrict__ mtF)
{
  int y = blockIdx.y;
  const u16* W; u16* F; int gofs = 0;
  switch (y) {
    case 0: W = qwT; F = qkF; break;
    case 1: W = kwT; F = qkF; gofs = 32; break;
    case 2: W = vwT; F = vwF; break;
    case 3: W = owB; F = owF; break;
    case 4: W = rdB; F = rdF; break;
    case 5: W = wrB; F = wrF; break;
    default: W = mtB; F = mtF; break;
  }
  int idx = blockIdx.x * 256 + threadIdx.x;   // 32768 per matrix
  int n = idx >> 6, k8 = idx & 63;
  bvec4 v0 = *(const bvec4*)&W[(size_t)n * DD + k8 * 8];
  bvec4 v1 = *(const bvec4*)&W[(size_t)n * DD + k8 * 8 + 4];
  size_t o = ((size_t)((gofs + (n >> 4)) * 16 + (k8 >> 2)) * 64 + (n & 15) + (k8 & 3) * 16) * 8;
  *(bvec4*)&F[o] = v0;
  *(bvec4*)&F[o + 4] = v1;
}

// ---- xb[m][k] = bf16( x[m][k] * rsqrt(mean(x[m]^2)+eps) ); one wave per row ----
__global__ __launch_bounds__(256) void xbconv_kernel(const float* __restrict__ x,
                                                     u16* __restrict__ xb)
{
  int row = blockIdx.x * 4 + (threadIdx.x >> 6);
  int lane = threadIdx.x & 63;
  const float4* p = (const float4*)(x + (size_t)row * DD);
  float4 a = p[lane * 2], b = p[lane * 2 + 1];
  float ss = a.x*a.x + a.y*a.y + a.z*a.z + a.w*a.w
           + b.x*b.x + b.y*b.y + b.z*b.z + b.w*b.w;
  ss = wred_sum(ss);
  float rs = rsqrtf(ss * (1.f / 512.f) + EPS_RMS);
  union { bvec8 s; u16 u[8]; } o;
  o.u[0]=f2bf(a.x*rs); o.u[1]=f2bf(a.y*rs); o.u[2]=f2bf(a.z*rs); o.u[3]=f2bf(a.w*rs);
  o.u[4]=f2bf(b.x*rs); o.u[5]=f2bf(b.y*rs); o.u[6]=f2bf(b.z*rs); o.u[7]=f2bf(b.w*rs);
  *(bvec8*)&xb[(size_t)row * DD + lane * 8] = o.s;
}

// ---- row softmax (512 elems) of fp32 logits -> bf16 ----
__global__ __launch_bounds__(256) void softmax_row_kernel(const float* __restrict__ logit,
                                                          u16* __restrict__ outb)
{
  int row = blockIdx.x * 4 + (threadIdx.x >> 6);
  int lane = threadIdx.x & 63;
  const float4* p = (const float4*)(logit + (size_t)row * DD);
  float4 a = p[lane * 2], b = p[lane * 2 + 1];
  float m = fmaxf(fmaxf(fmaxf(a.x, a.y), fmaxf(a.z, a.w)),
                  fmaxf(fmaxf(b.x, b.y), fmaxf(b.z, b.w)));
  m = wred_max(m);
  float e0=expf(a.x-m), e1=expf(a.y-m), e2=expf(a.z-m), e3=expf(a.w-m);
  float e4=expf(b.x-m), e5=expf(b.y-m), e6=expf(b.z-m), e7=expf(b.w-m);
  float s = wred_sum(e0+e1+e2+e3+e4+e5+e6+e7);
  float inv = 1.f / s;
  union { bvec8 sv; u16 u[8]; } o;
  o.u[0]=f2bf(e0*inv); o.u[1]=f2bf(e1*inv); o.u[2]=f2bf(e2*inv); o.u[3]=f2bf(e3*inv);
  o.u[4]=f2bf(e4*inv); o.u[5]=f2bf(e5*inv); o.u[6]=f2bf(e6*inv); o.u[7]=f2bf(e7*inv);
  *(bvec8*)&outb[(size_t)row * DD + lane * 8] = o.sv;
}

// ---- mixT[n][k] = bf16(mix[k][n]) ----
__global__ __launch_bounds__(256) void mixT_kernel(const float* __restrict__ mix,
                                                   u16* __restrict__ mt)
{
  int idx = blockIdx.x * 256 + threadIdx.x;
  int n = idx & 511, k = idx >> 9;
  mt[(size_t)n * DD + k] = f2bf(mix[idx]);
}

// ---- finish rms scales ----
__global__ __launch_bounds__(256) void rsfin_kernel(float* __restrict__ ssq)
{
  int i = blockIdx.x * 256 + threadIdx.x;
  ssq[i] = rsqrtf(ssq[i] * (1.f / 512.f) + EPS_RMS);
}

// ================= main MFMA GEMM (hybrid core) =================
template<int MODE>
__global__ __launch_bounds__(256, 3) void mfma1d(
    const u16* __restrict__ A,        // staged operand base
    const u16* __restrict__ Bn,       // natural direct base
    const u16* __restrict__ Bp,       // packed direct base
    void* outp, void* out2, void* out3, int ldo,
    const float* __restrict__ resid, const float* __restrict__ bias,
    const float* __restrict__ s0, const float* __restrict__ s1,
    const float* __restrict__ dlog, float* __restrict__ ssq,
    const float* __restrict__ rsv, int NT)
{
  constexpr bool SA = (MODE != M_VT);
  constexpr bool PK = (MODE == M_QK || MODE == M_VT || MODE == M_ORES ||
                       MODE == M_RSCALE || MODE == M_GELU || MODE == M_F32RES);
  __shared__ __align__(16) u16 lds[16384];
  int tid = threadIdx.x, lane = tid & 63, wave = tid >> 6;
  int wm = (wave >> 1) * 64, wn = (wave & 1) * 64;

  const u16* Sg;
  const u16* Dn = nullptr;
  int db16 = 0;
  size_t om, on;
  int bxx = 0, byy = 0, bzz = 0;
  int ldb = DD;

  if constexpr (MODE == M_QK) {
    int nb = xcd_swz(blockIdx.x, 128);         // 1024 blocks: 128 m x 8 n
    int m = nb >> 3, n = nb & 7;
    Sg = A + (size_t)m * 128 * DD;
    db16 = n * 8;
    om = (size_t)m * 128; on = (size_t)n * 128;
  } else if constexpr (MODE == M_VT) {
    int nb = xcd_swz(blockIdx.x, 64);          // 512 blocks: 4 m(c) x 128 n(t), n-major
    int n = nb >> 2, m = nb & 3;
    Sg = A + (size_t)n * 128 * DD;             // staged = xb rows (t side)
    db16 = m * 8;                              // direct = vwF (c side)
    om = (size_t)m * 128; on = (size_t)n * 128;
  } else if constexpr (MODE == M_SCORE) {
    int nb = xcd_swz(blockIdx.x, 48);          // 384 blocks
    bxx = nb % 3; int rr = nb / 3; byy = rr & 31; bzz = rr >> 5;
    Sg = A + (size_t)(bzz * TLEN + byy * 128) * DD;
    Dn = Bn + (size_t)(bzz * TLEN + (byy + bxx) * 128) * DD;
    om = (size_t)(bzz * NT128 + byy) * 128; on = (size_t)bxx * 128;
  } else if constexpr (MODE == M_RET) {
    int nb = xcd_swz(blockIdx.x, 64);          // 512 blocks
    bxx = nb & 3; int rr = nb >> 2; byy = rr & 31; bzz = rr >> 5;
    Sg = A + (size_t)((bzz * NT128 + byy) * 128) * SWB;
    Dn = Bn + (size_t)(bxx * 128) * MROWS + (size_t)(bzz * TLEN + byy * 128);
    ldb = MROWS;
    om = (size_t)(bzz * TLEN + byy * 128); on = (size_t)bxx * 128;
  } else {
    int nb = xcd_swz(blockIdx.x, 64);          // 512 blocks: 4 n x 128 m
    bxx = nb & 3; byy = nb >> 2;
    Sg = A + (size_t)byy * 128 * DD;
    db16 = bxx * 8;
    om = (size_t)byy * 128; on = (size_t)bxx * 128;
  }

  int lda = (MODE == M_RET) ? SWB : DD;
  fvec4 acc[4][4] = {};
  gcore_h<SA, PK>(Sg, lda, Dn, ldb, Bp, db16, lds, NT, tid,
                  SA ? wm : wn, SA ? wn : wm, acc, 16);

  int l15 = lane & 15, lr4 = (lane >> 4) << 2;
  float dlw = 0.f;
  if constexpr (MODE == M_SCORE) {
    float dl = *dlog;
    float dc = 1.f / (1.f + expf(-dl));
    dlw = log2f(dc);
  }
  float alpha = 1.f;
  if constexpr (MODE == M_ORES || MODE == M_F32RES) alpha = s0[0] * s1[0];

  float ss[4][4] = {};

#pragma unroll
  for (int mi = 0; mi < 4; ++mi) {
#pragma unroll
    for (int ni = 0; ni < 4; ++ni) {
#pragma unroll
      for (int j = 0; j < 4; ++j) {
        int rl = wm + mi * 16 + lr4 + j;
        int cl = wn + ni * 16 + l15;
        float v = acc[mi][ni][j];
        size_t r = om + rl, c = on + cl;
        if constexpr (MODE == M_QK) {
          u16* o = (c < 512) ? (u16*)outp : (u16*)out2;
          o[r * 512 + (c & 511)] = f2bf(v);
        } else if constexpr (MODE == M_VT) {
          ((u16*)out3)[r * (size_t)MROWS + c] = f2bf(v);   // vT[c][t]
        } else if constexpr (MODE == M_SCORE) {
          int d = bxx * 128 + (int)cl - rl;
          int sidx = (byy + bxx) * 128 + (int)cl;
          float w2 = (d >= 1 && sidx < TLEN) ? exp2f((float)(d - 1) * dlw) : 0.f;
          ((u16*)outp)[r * (size_t)ldo + c] = f2bf(v * w2);
        } else if constexpr (MODE == M_ORES) {
          size_t o = r * (size_t)ldo + c;
          float t = resid[o] + alpha * v;
          ((float*)outp)[o] = t;
          ((u16*)out2)[o] = f2bf(t);
          ss[mi][j] += t * t;
        } else if constexpr (MODE == M_F32RES) {
          size_t o = r * (size_t)ldo + c;
          ((float*)outp)[o] = resid[o] + alpha * v;
        } else if constexpr (MODE == M_RSCALE) {
          ((u16*)outp)[r * (size_t)ldo + c] = f2bf(v * rsv[r]);
        } else if constexpr (MODE == M_GELU) {
          float t = v + bias[c];
          float g = 0.5f * t * (1.f + erff(t * 0.70710678118654752f));
          ((u16*)outp)[r * (size_t)ldo + c] = f2bf(g);
        } else { // M_RET
          ((u16*)outp)[r * (size_t)ldo + c] = f2bf(v);
        }
      }
    }
  }

  if constexpr (MODE == M_ORES) {
#pragma unroll
    for (int mi = 0; mi < 4; ++mi)
#pragma unroll
      for (int j = 0; j < 4; ++j) {
        float s = ss[mi][j];
        s += __shfl_xor(s, 1, 64);
        s += __shfl_xor(s, 2, 64);
        s += __shfl_xor(s, 4, 64);
        s += __shfl_xor(s, 8, 64);
        if (l15 == 0) atomicAdd(&ssq[om + wm + mi * 16 + lr4 + j], s);
      }
  }
}

extern "C" void kernel_launch(void* const* d_in, const int* in_sizes, int n_in,
                              void* d_out, int out_size, void* d_ws, size_t ws_size,
                              hipStream_t stream) {
  const float* x       = (const float*)d_in[0];
  const float* basis   = (const float*)d_in[1];
  const float* qc      = (const float*)d_in[2];
  const float* kc      = (const float*)d_in[3];
  const float* vc      = (const float*)d_in[4];
  const float* oc      = (const float*)d_in[5];
  const float* decay_l = (const float*)d_in[6];
  const float* mos     = (const float*)d_in[7];
  const float* rc      = (const float*)d_in[8];
  const float* wc      = (const float*)d_in[9];
  const float* mix     = (const float*)d_in[10];
  const float* bias    = (const float*)d_in[11];
  const float* oos     = (const float*)d_in[12];
  const float* msc     = (const float*)d_in[13];
  const float* osc     = (const float*)d_in[14];
  float* out = (float*)d_out;

  char* w = (char*)d_ws;
  u16* basisb = (u16*)w; w += 65536 * 2;
  u16* qcb    = (u16*)w; w += 65536 * 2;
  u16* kcb    = (u16*)w; w += 65536 * 2;
  u16* vcb    = (u16*)w; w += 65536 * 2;
  u16* ocb    = (u16*)w; w += 65536 * 2;
  u16* rcb    = (u16*)w; w += 65536 * 2;
  u16* wcb    = (u16*)w; w += 65536 * 2;
  u16* qwT = (u16*)w; w += 262144 * 2;
  u16* kwT = (u16*)w; w += 262144 * 2;
  u16* vwT = (u16*)w; w += 262144 * 2;
  u16* owB = (u16*)w; w += 262144 * 2;
  u16* rdB = (u16*)w; w += 262144 * 2;
  u16* wrB = (u16*)w; w += 262144 * 2;
  u16* mtB = (u16*)w; w += 262144 * 2;
  u16* qkF = (u16*)w; w += 524288 * 2;  // packed q|k weights [64 g16][16][64][8]
  u16* vwF = (u16*)w; w += 262144 * 2;
  u16* owF = (u16*)w; w += 262144 * 2;
  u16* rdF = (u16*)w; w += 262144 * 2;
  u16* wrF = (u16*)w; w += 262144 * 2;
  u16* mtF = (u16*)w; w += 262144 * 2;
  float* readLog = (float*)w; w += 262144 * 4;
  float* ssq = (float*)w; w += 16384 * 4;
  u16* xb = (u16*)w; w += (size_t)MROWS * DD * 2;
  u16* qb = (u16*)w; w += (size_t)MROWS * DD * 2;
  u16* kb = (u16*)w; w += (size_t)(MROWS + 640) * DD * 2;
  u16* vT = (u16*)w; w += ((size_t)DD * MROWS + 2048) * 2;
  u16* sc = (u16*)w; w += (size_t)MROWS * SWB * 2;
  u16* ret = (u16*)w; w += (size_t)MROWS * DD * 2;

  hipMemsetAsync(ssq, 0, 16384 * sizeof(float), stream);
  conv7_kernel<<<dim3(64, 7), 256, 0, stream>>>(basis, qc, kc, vc, oc, rc, wc,
                                                basisb, qcb, kcb, vcb, ocb, rcb, wcb);
  wgen_kernel<<<dim3(4, 4, 6), 256, 0, stream>>>(basisb, qcb, kcb, vcb, ocb, wcb, rcb,
                                                 qwT, kwT, vwT, owB, wrB, readLog);
  softmax_row_kernel<<<128, 256, 0, stream>>>(readLog, rdB);
  mixT_kernel<<<1024, 256, 0, stream>>>(mix, mtB);
  repack7_kernel<<<dim3(128, 7), 256, 0, stream>>>(qwT, kwT, vwT, owB, rdB, wrB, mtB,
                                                   qkF, vwF, owF, rdF, wrF, mtF);
  xbconv_kernel<<<4096, 256, 0, stream>>>(x, xb);
  // q,k projections (N=1024 merged, packed weights)
  mfma1d<M_QK><<<1024, 256, 0, stream>>>(xb, nullptr, qkF, qb, kb, nullptr, DD,
                                         nullptr, nullptr, nullptr, nullptr, nullptr, nullptr, nullptr, 8);
  // vT[c][t] (staged xb as col-side, packed vwF as row-side)
  mfma1d<M_VT><<<512, 256, 0, stream>>>(xb, nullptr, vwF, nullptr, nullptr, vT, MROWS,
                                        nullptr, nullptr, nullptr, nullptr, nullptr, nullptr, nullptr, 8);
  // banded decayed scores
  mfma1d<M_SCORE><<<384, 256, 0, stream>>>(qb, kb, nullptr, sc, nullptr, nullptr, SWB,
                                           nullptr, nullptr, nullptr, nullptr, decay_l, nullptr, nullptr, 8);
  // retrieved = band(scores) @ v
  mfma1d<M_RET><<<512, 256, 0, stream>>>(sc, vT, nullptr, ret, nullptr, nullptr, DD,
                                         nullptr, nullptr, nullptr, nullptr, nullptr, nullptr, nullptr, 6);
  // x1 = x + msc*mos*(ret @ o_w.T); bf16(x1)->xb; row-sumsq->ssq
  mfma1d<M_ORES><<<512, 256, 0, stream>>>(ret, nullptr, owF, out, xb, nullptr, DD,
                                          x, nullptr, msc, mos, nullptr, ssq, nullptr, 8);
  rsfin_kernel<<<64, 256, 0, stream>>>(ssq);
  // tmp = rmsnorm(x1) @ read_w
  mfma1d<M_RSCALE><<<512, 256, 0, stream>>>(xb, nullptr, rdF, qb, nullptr, nullptr, DD,
                                            nullptr, nullptr, nullptr, nullptr, nullptr, nullptr, ssq, 8);
  // vals = gelu(tmp @ mix + bias)
  mfma1d<M_GELU><<<512, 256, 0, stream>>>(qb, nullptr, mtF, kb, nullptr, nullptr, DD,
                                          nullptr, bias, nullptr, nullptr, nullptr, nullptr, nullptr, 8);
  // out = x1 + osc*oos*(vals @ write_w.T)
  mfma1d<M_F32RES><<<512, 256, 0, stream>>>(kb, nullptr, wrF, out, nullptr, nullptr, DD,
                                            out, nullptr, osc, oos, nullptr, nullptr, nullptr, 8);
}